// Round 4
// baseline (4390.120 us; speedup 1.0000x reference)
//
#include <hip/hip_runtime.h>

// ---------------------------------------------------------------- types
typedef __bf16  b8v   __attribute__((ext_vector_type(8)));
typedef float   f32x4 __attribute__((ext_vector_type(4)));
typedef float   f32v4 __attribute__((ext_vector_type(4)));
typedef short   s4v   __attribute__((ext_vector_type(4)));
typedef short   s8v   __attribute__((ext_vector_type(8)));
typedef int     i4v   __attribute__((ext_vector_type(4)));

#define M_TOK 16384   // S*B
#define S_    64
#define B_    256
#define D_    1024
#define F_    4096
#define E_    4
#define OUT_  512

__device__ __forceinline__ short f2bf(float f) {
    unsigned u = __builtin_bit_cast(unsigned, f);
    u += 0x7fffu + ((u >> 16) & 1u);          // RNE
    return (short)(u >> 16);
}
__device__ __forceinline__ float bf2f(short s) {
    unsigned u = ((unsigned)(unsigned short)s) << 16;
    return __builtin_bit_cast(float, u);
}
__device__ __forceinline__ void gll16(const short* g, short* l) {
    __builtin_amdgcn_global_load_lds(
        (__attribute__((address_space(1))) void*)(void*)const_cast<short*>(g),
        (__attribute__((address_space(3))) void*)l, 16, 0, 0);
}

// ---------------------------------------------------------------- GEMM
// C[M,N] = A[M,K](bf16) @ Wt[N,K](bf16, pre-transposed) + bias
// EPI: 0 = bf16 out, 1 = relu->bf16 out, 2 = MoE: acc[perm] += coef*val, 3 = fp32 out
template<int EPI>
__global__ __launch_bounds__(256)
void gemm_k(const short* __restrict__ A, const short* __restrict__ Bt,
            const float* __restrict__ bias,
            short* __restrict__ outb, float* __restrict__ outf,
            int M, int N, int K,
            const float* __restrict__ coef, float* __restrict__ accp)
{
    __shared__ __align__(16) short Al[128 * 32];
    __shared__ __align__(16) short Bl[128 * 32];
    const int tid  = threadIdx.x;
    const int lane = tid & 63;
    const int wid  = tid >> 6;
    const int wr   = (wid >> 1) * 64;
    const int wc   = (wid & 1) * 64;
    const int bn   = blockIdx.x, bm = blockIdx.y;
    const int r    = lane & 15, q = lane >> 4;

    const short* Ag = A  + (size_t)(bm * 128 + (tid >> 2)) * K + (tid & 3) * 8;
    const short* Bg = Bt + (size_t)(bn * 128 + (tid >> 2)) * K + (tid & 3) * 8;
    short* Ald = Al + tid * 8;
    short* Bld = Bl + tid * 8;

    f32x4 acc[4][4] = {};
    const int nk = K >> 5;
    for (int kt = 0; kt < nk; ++kt) {
        __syncthreads();
        gll16(Ag,                     Ald);
        gll16(Ag + (size_t)64 * K,    Ald + 2048);
        gll16(Bg,                     Bld);
        gll16(Bg + (size_t)64 * K,    Bld + 2048);
        Ag += 32; Bg += 32;
        __syncthreads();
        b8v af[4], bfr[4];
        #pragma unroll
        for (int i = 0; i < 4; i++)
            af[i]  = *(const b8v*)(Al + (wr + i * 16 + r) * 32 + q * 8);
        #pragma unroll
        for (int i = 0; i < 4; i++)
            bfr[i] = *(const b8v*)(Bl + (wc + i * 16 + r) * 32 + q * 8);
        #pragma unroll
        for (int i = 0; i < 4; i++)
            #pragma unroll
            for (int j = 0; j < 4; j++)
                acc[i][j] = __builtin_amdgcn_mfma_f32_16x16x32_bf16(
                                af[i], bfr[j], acc[i][j], 0, 0, 0);
    }
    // epilogue: C/D frag layout col=lane&15 (=r), row=(lane>>4)*4+reg (m89-verified)
    float bv[4];
    #pragma unroll
    for (int j = 0; j < 4; j++) bv[j] = bias[bn * 128 + wc + j * 16 + r];
    #pragma unroll
    for (int i = 0; i < 4; i++) {
        const int row0 = bm * 128 + wr + i * 16 + q * 4;
        #pragma unroll
        for (int j = 0; j < 4; j++) {
            const int col = bn * 128 + wc + j * 16 + r;
            #pragma unroll
            for (int jj = 0; jj < 4; jj++) {
                const int row = row0 + jj;
                float v = acc[i][j][jj] + bv[j];
                if (EPI == 1) v = fmaxf(v, 0.f);
                if (EPI <= 1) {
                    outb[(size_t)row * N + col] = f2bf(v);
                } else if (EPI == 2) {
                    const int b = row & 255, s = row >> 8;   // row = s*256+b
                    accp[(size_t)(b * 64 + s) * N + col] += coef[b] * v;
                } else {
                    outf[(size_t)row * N + col] = v;
                }
            }
        }
    }
}

// ---------------------------------------------------------------- attention
__global__ __launch_bounds__(256)
void attn_k(const short* __restrict__ qkv, short* __restrict__ o)
{
    __shared__ __align__(16) short ql[64][72], kl[64][72], vt[64][72], pl[64][72];
    const int bh = blockIdx.x;
    const int b = bh >> 4, h = bh & 15;
    const int tid = threadIdx.x;
    for (int c = tid; c < 512; c += 256) {
        const int s = c >> 3, d0 = (c & 7) * 8;
        const short* gp = qkv + (size_t)(s * B_ + b) * 3072 + h * 64 + d0;
        *(i4v*)&ql[s][d0] = *(const i4v*)gp;
        *(i4v*)&kl[s][d0] = *(const i4v*)(gp + 1024);
        s8v vv = *(const s8v*)(gp + 2048);
        #pragma unroll
        for (int i = 0; i < 8; i++) vt[d0 + i][s] = vv[i];   // V^T: vt[d][t]
    }
    __syncthreads();
    const int lane = tid & 63, w = tid >> 6;
    const int r = lane & 15, q = lane >> 4;

    f32x4 sc[4] = {};
    #pragma unroll
    for (int kt = 0; kt < 2; ++kt) {
        b8v aq = *(const b8v*)&ql[w * 16 + r][kt * 32 + q * 8];
        #pragma unroll
        for (int nn = 0; nn < 4; nn++) {
            b8v bk = *(const b8v*)&kl[nn * 16 + r][kt * 32 + q * 8];
            sc[nn] = __builtin_amdgcn_mfma_f32_16x16x32_bf16(aq, bk, sc[nn], 0, 0, 0);
        }
    }
    // softmax over t: lane holds rows s=w*16+q*4+j, cols t=nn*16+r
    #pragma unroll
    for (int j = 0; j < 4; j++) {
        float m = fmaxf(fmaxf(sc[0][j], sc[1][j]), fmaxf(sc[2][j], sc[3][j]));
        #pragma unroll
        for (int d = 1; d < 16; d <<= 1) m = fmaxf(m, __shfl_xor(m, d));
        float p[4], sum = 0.f;
        #pragma unroll
        for (int nn = 0; nn < 4; nn++) {
            p[nn] = __expf((sc[nn][j] - m) * 0.125f);   // fold 1/sqrt(64)
            sum += p[nn];
        }
        #pragma unroll
        for (int d = 1; d < 16; d <<= 1) sum += __shfl_xor(sum, d);
        const float inv = 1.f / sum;
        #pragma unroll
        for (int nn = 0; nn < 4; nn++)
            pl[w * 16 + q * 4 + j][nn * 16 + r] = f2bf(p[nn] * inv);
    }
    __syncthreads();
    f32x4 oc[4] = {};
    #pragma unroll
    for (int kt = 0; kt < 2; ++kt) {
        b8v ap = *(const b8v*)&pl[w * 16 + r][kt * 32 + q * 8];
        #pragma unroll
        for (int nn = 0; nn < 4; nn++) {
            b8v bv = *(const b8v*)&vt[nn * 16 + r][kt * 32 + q * 8];
            oc[nn] = __builtin_amdgcn_mfma_f32_16x16x32_bf16(ap, bv, oc[nn], 0, 0, 0);
        }
    }
    #pragma unroll
    for (int nn = 0; nn < 4; nn++)
        #pragma unroll
        for (int j = 0; j < 4; j++) {
            const int s = w * 16 + q * 4 + j;
            o[(size_t)(s * B_ + b) * 1024 + h * 64 + nn * 16 + r] = f2bf(oc[nn][j]);
        }
}

// ---------------------------------------------------------------- LayerNorm
template<int OUTP>
__global__ __launch_bounds__(256)
void ln_k(const short* __restrict__ xin, const short* __restrict__ resid,
          const float* __restrict__ gam, const float* __restrict__ bet,
          short* __restrict__ outb, float* __restrict__ outf)
{
    const int row = blockIdx.x, tid = threadIdx.x;
    const s4v xs = ((const s4v*)(xin   + (size_t)row * 1024))[tid];
    const s4v rs = ((const s4v*)(resid + (size_t)row * 1024))[tid];
    float v[4], s = 0.f, s2 = 0.f;
    #pragma unroll
    for (int i = 0; i < 4; i++) {
        v[i] = bf2f(xs[i]) + bf2f(rs[i]);
        s += v[i]; s2 += v[i] * v[i];
    }
    #pragma unroll
    for (int d = 1; d < 64; d <<= 1) { s += __shfl_xor(s, d); s2 += __shfl_xor(s2, d); }
    __shared__ float red[8];
    const int wid = tid >> 6, lane = tid & 63;
    if (lane == 0) { red[wid] = s; red[4 + wid] = s2; }
    __syncthreads();
    s  = red[0] + red[1] + red[2] + red[3];
    s2 = red[4] + red[5] + red[6] + red[7];
    const float mean = s * (1.f / 1024.f);
    const float var  = s2 * (1.f / 1024.f) - mean * mean;
    const float rstd = rsqrtf(var + 1e-5f);
    const f32v4 g4 = ((const f32v4*)gam)[tid];
    const f32v4 b4 = ((const f32v4*)bet)[tid];
    if (OUTP == 0) {
        s4v ov;
        #pragma unroll
        for (int i = 0; i < 4; i++) ov[i] = f2bf((v[i] - mean) * rstd * g4[i] + b4[i]);
        ((s4v*)(outb + (size_t)row * 1024))[tid] = ov;
    } else {
        f32v4 ov;
        #pragma unroll
        for (int i = 0; i < 4; i++) ov[i] = (v[i] - mean) * rstd * g4[i] + b4[i];
        ((f32v4*)(outf + (size_t)((row & 255) * 64 + (row >> 8)) * 1024))[tid] = ov;
    }
}

// ---------------------------------------------------------------- gate
__global__ __launch_bounds__(256)
void gate_k(const float* __restrict__ cat, const float* __restrict__ W1,
            const float* __restrict__ b1, const float* __restrict__ W2,
            const float* __restrict__ b2, float* __restrict__ coef,
            float* __restrict__ outscalar)
{
    const int b = blockIdx.x, tid = threadIdx.x;
    __shared__ float g[2048];
    __shared__ float h[256];
    __shared__ float lg[5];
    for (int i = tid; i < 1024; i += 256) {
        g[i]        = cat[(size_t)b * 1024 + i];             // prop (s=0)
        g[1024 + i] = cat[(size_t)(B_ + b) * 1024 + i];      // refe (s=1)
    }
    __syncthreads();
    float a = b1[tid];
    for (int d = 0; d < 2048; ++d) a += g[d] * W1[(size_t)d * 256 + tid];
    h[tid] = fmaxf(a, 0.f);
    __syncthreads();
    if (tid < 5) {
        float l = b2[tid];
        for (int i = 0; i < 256; ++i) l += h[i] * W2[i * 5 + tid];
        lg[tid] = l;
    }
    __syncthreads();
    if (tid == 0) {
        float l[5]; int ks = 0; float mx;
        #pragma unroll
        for (int j = 0; j < 5; j++) l[j] = lg[j];
        mx = l[0];
        for (int j = 1; j < 5; j++) if (l[j] > mx) { mx = l[j]; ks = j; }
        float e[5], se = 0.f;
        #pragma unroll
        for (int j = 0; j < 5; j++) { e[j] = expf(l[j] - mx); se += e[j]; }
        for (int ee = 0; ee < 4; ++ee) {
            float wv = 0.f;
            for (int j = ee + 1; j < 5; ++j) wv += e[j];
            coef[ee * B_ + b] = (ks >= ee + 1) ? (wv / se) : 0.f;
        }
    }
    if (b == 0 && tid == 0) outscalar[0] = 0.f;   // tuple's second output
}

// ---------------------------------------------------------------- converters
// fp32 [K][N] -> bf16 [N][K]
__global__ __launch_bounds__(256)
void tconv_k(const float* __restrict__ in, short* __restrict__ out, int K, int N)
{
    __shared__ float t[32][33];
    const int bx = blockIdx.x, by = blockIdx.y;
    const int tx = threadIdx.x & 31, ty = threadIdx.x >> 5;
    #pragma unroll
    for (int i = 0; i < 32; i += 8)
        t[ty + i][tx] = in[(size_t)(by * 32 + ty + i) * N + bx * 32 + tx];
    __syncthreads();
    #pragma unroll
    for (int i = 0; i < 32; i += 8)
        out[(size_t)(bx * 32 + ty + i) * K + by * 32 + tx] = f2bf(t[tx][ty + i]);
}

__global__ __launch_bounds__(256)
void f2bf_k(const float* __restrict__ in, short* __restrict__ out, int n4)
{
    const int i = blockIdx.x * 256 + threadIdx.x;
    if (i < n4) {
        const f32v4 v = ((const f32v4*)in)[i];
        s4v o;
        #pragma unroll
        for (int j = 0; j < 4; j++) o[j] = f2bf(v[j]);
        ((s4v*)out)[i] = o;
    }
}

// diagnostic: absmax ~= ws_size tells us the workspace was too small
__global__ void diag_k(float* out, float val) { out[0] = val; }

// ---------------------------------------------------------------- launch
extern "C" void kernel_launch(void* const* d_in, const int* in_sizes, int n_in,
                              void* d_out, int out_size, void* d_ws, size_t ws_size,
                              hipStream_t stream)
{
    const float* cat   = (const float*)d_in[0];
    const float* gW1   = (const float*)d_in[1];
    const float* gb1   = (const float*)d_in[2];
    const float* gW2   = (const float*)d_in[3];
    const float* gb2   = (const float*)d_in[4];
    const float* zW    = (const float*)d_in[29];
    const float* zb    = (const float*)d_in[30];
    const float* outW  = (const float*)d_in[31];
    const float* outb_ = (const float*)d_in[32];

    char* w = (char*)d_ws;
    size_t off = 0;
    auto alloc = [&](size_t bytes) { void* p = w + off; off = (off + bytes + 255) & ~(size_t)255; return p; };
    // per-layer weight staging (reused across the 5 encoder layers)
    short* wq    = (short*)alloc((size_t)3072 * 1024 * 2);
    short* wo    = (short*)alloc((size_t)1024 * 1024 * 2);
    short* w1t   = (short*)alloc((size_t)4096 * 1024 * 2);
    short* w2t   = (short*)alloc((size_t)1024 * 4096 * 2);
    short* wz    = (short*)alloc((size_t)1024 * 1024 * 2);
    short* outWT = (short*)alloc((size_t)512 * 1024 * 2);
    short* catbf = (short*)alloc((size_t)M_TOK * 1024 * 2);
    short* big   = (short*)alloc((size_t)M_TOK * 4096 * 2);   // qkv (100MB) / h1 (134MB)
    short* tmp   = (short*)alloc((size_t)M_TOK * 1024 * 2);
    short* x1    = (short*)alloc((size_t)M_TOK * 1024 * 2);
    float* acc   = (float*)alloc((size_t)M_TOK * 1024 * 4);
    float* coef  = (float*)alloc((size_t)4 * 256 * 4);
    // attn-out / x2 aliases big's tail (qkv only uses 16384*3072 of big;
    // lifetimes verified: attn reads big[0,100M) writes big[100M,134M);
    // FFN1 overwrites big only after attn-out dead; ln2's x2 write to the
    // tail happens after h1 dead; zW GEMM reads it before next layer's QKV.
    short* attno = big + (size_t)M_TOK * 3072;
    (void)n_in; (void)in_sizes;

    if (off > ws_size) {   // workspace too small: fail cleanly + report size
        hipMemsetAsync(d_out, 0, (size_t)out_size * 4, stream);
        diag_k<<<1, 1, 0, stream>>>((float*)d_out, (float)ws_size);
        return;
    }

    // one-time conversions
    tconv_k<<<dim3(16, 32), 256, 0, stream>>>(outW, outWT, 1024, 512);
    f2bf_k<<<16384, 256, 0, stream>>>(cat, catbf, M_TOK * 1024 / 4);

    // gate (also writes the tuple's scalar 0.0)
    gate_k<<<B_, 256, 0, stream>>>(cat, gW1, gb1, gW2, gb2, coef,
                                   (float*)d_out + (size_t)M_TOK * OUT_);

    auto encoder = [&](int enc, bool base) {
        const int e = enc - 1;
        const float *Wq_f, *Wo_f, *W1_f, *W2_f;
        const float *bq, *bo, *l1g, *l1b, *bf1, *bf2, *l2g, *l2b;
        if (base) {
            Wq_f = (const float*)d_in[5];  W1_f = (const float*)d_in[11];
            Wo_f = (const float*)d_in[7];  W2_f = (const float*)d_in[13];
            bq  = (const float*)d_in[6];  bo  = (const float*)d_in[8];
            l1g = (const float*)d_in[9];  l1b = (const float*)d_in[10];
            bf1 = (const float*)d_in[12]; bf2 = (const float*)d_in[14];
            l2g = (const float*)d_in[15]; l2b = (const float*)d_in[16];
        } else {
            Wq_f = (const float*)d_in[17] + (size_t)e * 1024 * 3072;
            Wo_f = (const float*)d_in[19] + (size_t)e * 1024 * 1024;
            W1_f = (const float*)d_in[23] + (size_t)e * 1024 * 4096;
            W2_f = (const float*)d_in[25] + (size_t)e * 4096 * 1024;
            bq  = (const float*)d_in[18] + (size_t)e * 3072;
            bo  = (const float*)d_in[20] + (size_t)e * 1024;
            l1g = (const float*)d_in[21] + (size_t)e * 1024;
            l1b = (const float*)d_in[22] + (size_t)e * 1024;
            bf1 = (const float*)d_in[24] + (size_t)e * 4096;
            bf2 = (const float*)d_in[26] + (size_t)e * 1024;
            l2g = (const float*)d_in[27] + (size_t)e * 1024;
            l2b = (const float*)d_in[28] + (size_t)e * 1024;
        }
        // per-layer weight conversion into the shared staging buffers
        tconv_k<<<dim3(96, 32),  256, 0, stream>>>(Wq_f, wq,  1024, 3072);
        tconv_k<<<dim3(32, 32),  256, 0, stream>>>(Wo_f, wo,  1024, 1024);
        tconv_k<<<dim3(128, 32), 256, 0, stream>>>(W1_f, w1t, 1024, 4096);
        tconv_k<<<dim3(32, 128), 256, 0, stream>>>(W2_f, w2t, 4096, 1024);
        if (!base)
            tconv_k<<<dim3(32, 32), 256, 0, stream>>>(zW + (size_t)e * 1024 * 1024, wz, 1024, 1024);

        gemm_k<0><<<dim3(24, 128), 256, 0, stream>>>(catbf, wq, bq, big, nullptr,
                                                     M_TOK, 3072, 1024, nullptr, nullptr);
        attn_k<<<B_ * 16, 256, 0, stream>>>(big, attno);
        gemm_k<0><<<dim3(8, 128), 256, 0, stream>>>(attno, wo, bo, tmp, nullptr,
                                                    M_TOK, 1024, 1024, nullptr, nullptr);
        ln_k<0><<<M_TOK, 256, 0, stream>>>(tmp, catbf, l1g, l1b, x1, nullptr);
        gemm_k<1><<<dim3(32, 128), 256, 0, stream>>>(x1, w1t, bf1, big, nullptr,
                                                     M_TOK, 4096, 1024, nullptr, nullptr);
        gemm_k<0><<<dim3(8, 128), 256, 0, stream>>>(big, w2t, bf2, tmp, nullptr,
                                                    M_TOK, 1024, 4096, nullptr, nullptr);
        if (base) {
            ln_k<1><<<M_TOK, 256, 0, stream>>>(tmp, x1, l2g, l2b, nullptr, acc);
        } else {
            ln_k<0><<<M_TOK, 256, 0, stream>>>(tmp, x1, l2g, l2b, attno, nullptr);  // x2
            gemm_k<2><<<dim3(8, 128), 256, 0, stream>>>(attno, wz,
                                                        zb + (size_t)e * 1024, nullptr, nullptr,
                                                        M_TOK, 1024, 1024, coef + e * 256, acc);
        }
    };
    encoder(0, true);
    for (int e = 0; e < 4; ++e) encoder(e + 1, false);

    // final projection: out[b,s,:] = acc_row(b*64+s) @ out_W + out_b
    f2bf_k<<<16384, 256, 0, stream>>>(acc, x1, M_TOK * 1024 / 4);
    gemm_k<3><<<dim3(4, 128), 256, 0, stream>>>(x1, outWT, outb_, nullptr, (float*)d_out,
                                                M_TOK, 512, 1024, nullptr, nullptr);
}

// Round 6
// 4223.980 us; speedup vs baseline: 1.0393x; 1.0393x over previous
//
#include <hip/hip_runtime.h>

// ---------------------------------------------------------------- types
typedef __bf16  b8v   __attribute__((ext_vector_type(8)));
typedef float   f32x4 __attribute__((ext_vector_type(4)));
typedef float   f32v4 __attribute__((ext_vector_type(4)));
typedef short   s4v   __attribute__((ext_vector_type(4)));
typedef short   s8v   __attribute__((ext_vector_type(8)));
typedef int     i4v   __attribute__((ext_vector_type(4)));

#define M_TOK 16384   // S*B
#define S_    64
#define B_    256
#define D_    1024
#define F_    4096
#define E_    4
#define OUT_  512

__device__ __forceinline__ short f2bf(float f) {
    unsigned u = __builtin_bit_cast(unsigned, f);
    u += 0x7fffu + ((u >> 16) & 1u);          // RNE
    return (short)(u >> 16);
}
__device__ __forceinline__ float bf2f(short s) {
    unsigned u = ((unsigned)(unsigned short)s) << 16;
    return __builtin_bit_cast(float, u);
}
__device__ __forceinline__ void gll16(const short* g, short* l) {
    __builtin_amdgcn_global_load_lds(
        (__attribute__((address_space(1))) void*)(void*)const_cast<short*>(g),
        (__attribute__((address_space(3))) void*)l, 16, 0, 0);
}

// ---------------------------------------------------------------- GEMM
// C[M,N] = A[M,K](bf16) @ Wt[N,K](bf16, pre-transposed) + bias
// EPI: 0 = bf16 out, 1 = relu->bf16 out, 2 = MoE: acc[perm] += coef*val, 3 = fp32 out
// m97 structure + T1 XCD-aware swizzle: each XCD owns a contiguous bm-chunk
// so an A-panel lands in exactly one XCD L2 (was: replicated across all 8).
template<int EPI>
__global__ __launch_bounds__(256)
void gemm_k(const short* __restrict__ A, const short* __restrict__ Bt,
            const float* __restrict__ bias,
            short* __restrict__ outb, float* __restrict__ outf,
            int M, int N, int K,
            const float* __restrict__ coef, float* __restrict__ accp)
{
    __shared__ __align__(16) short Al[128 * 32];
    __shared__ __align__(16) short Bl[128 * 32];
    const int tid  = threadIdx.x;
    const int lane = tid & 63;
    const int wid  = tid >> 6;
    const int wr   = (wid >> 1) * 64;
    const int wc   = (wid & 1) * 64;

    // T1: XCD-aware chunked remap. HW round-robins linear bid across 8 XCDs;
    // remap so XCD x processes contiguous work ids [x*cpx, (x+1)*cpx).
    // All grids here have nwg % 8 == 0 (guarded anyway).
    const int nbn = gridDim.x;
    int d = blockIdx.y * nbn + blockIdx.x;
    const int nwg = nbn * (int)gridDim.y;
    if ((nwg & 7) == 0) {
        const int cpx = nwg >> 3;
        d = (d & 7) * cpx + (d >> 3);
    }
    const int bn = d % nbn, bm = d / nbn;

    const int r    = lane & 15, q = lane >> 4;

    const short* Ag = A  + (size_t)(bm * 128 + (tid >> 2)) * K + (tid & 3) * 8;
    const short* Bg = Bt + (size_t)(bn * 128 + (tid >> 2)) * K + (tid & 3) * 8;
    short* Ald = Al + tid * 8;
    short* Bld = Bl + tid * 8;

    f32x4 acc[4][4] = {};
    const int nk = K >> 5;
    for (int kt = 0; kt < nk; ++kt) {
        __syncthreads();
        gll16(Ag,                     Ald);
        gll16(Ag + (size_t)64 * K,    Ald + 2048);
        gll16(Bg,                     Bld);
        gll16(Bg + (size_t)64 * K,    Bld + 2048);
        Ag += 32; Bg += 32;
        __syncthreads();
        b8v af[4], bfr[4];
        #pragma unroll
        for (int i = 0; i < 4; i++)
            af[i]  = *(const b8v*)(Al + (wr + i * 16 + r) * 32 + q * 8);
        #pragma unroll
        for (int i = 0; i < 4; i++)
            bfr[i] = *(const b8v*)(Bl + (wc + i * 16 + r) * 32 + q * 8);
        #pragma unroll
        for (int i = 0; i < 4; i++)
            #pragma unroll
            for (int j = 0; j < 4; j++)
                acc[i][j] = __builtin_amdgcn_mfma_f32_16x16x32_bf16(
                                af[i], bfr[j], acc[i][j], 0, 0, 0);
    }
    // epilogue: C/D frag layout col=lane&15 (=r), row=(lane>>4)*4+reg (m89-verified)
    float bv[4];
    #pragma unroll
    for (int j = 0; j < 4; j++) bv[j] = bias[bn * 128 + wc + j * 16 + r];
    #pragma unroll
    for (int i = 0; i < 4; i++) {
        const int row0 = bm * 128 + wr + i * 16 + q * 4;
        #pragma unroll
        for (int j = 0; j < 4; j++) {
            const int col = bn * 128 + wc + j * 16 + r;
            #pragma unroll
            for (int jj = 0; jj < 4; jj++) {
                const int row = row0 + jj;
                float v = acc[i][j][jj] + bv[j];
                if (EPI == 1) v = fmaxf(v, 0.f);
                if (EPI <= 1) {
                    outb[(size_t)row * N + col] = f2bf(v);
                } else if (EPI == 2) {
                    const int b = row & 255, s = row >> 8;   // row = s*256+b
                    accp[(size_t)(b * 64 + s) * N + col] += coef[b] * v;
                } else {
                    outf[(size_t)row * N + col] = v;
                }
            }
        }
    }
}

// ---------------------------------------------------------------- attention
__global__ __launch_bounds__(256)
void attn_k(const short* __restrict__ qkv, short* __restrict__ o)
{
    __shared__ __align__(16) short ql[64][72], kl[64][72], vt[64][72], pl[64][72];
    const int bh = blockIdx.x;
    const int b = bh >> 4, h = bh & 15;
    const int tid = threadIdx.x;
    for (int c = tid; c < 512; c += 256) {
        const int s = c >> 3, d0 = (c & 7) * 8;
        const short* gp = qkv + (size_t)(s * B_ + b) * 3072 + h * 64 + d0;
        *(i4v*)&ql[s][d0] = *(const i4v*)gp;
        *(i4v*)&kl[s][d0] = *(const i4v*)(gp + 1024);
        s8v vv = *(const s8v*)(gp + 2048);
        #pragma unroll
        for (int i = 0; i < 8; i++) vt[d0 + i][s] = vv[i];   // V^T: vt[d][t]
    }
    __syncthreads();
    const int lane = tid & 63, w = tid >> 6;
    const int r = lane & 15, q = lane >> 4;

    f32x4 sc[4] = {};
    #pragma unroll
    for (int kt = 0; kt < 2; ++kt) {
        b8v aq = *(const b8v*)&ql[w * 16 + r][kt * 32 + q * 8];
        #pragma unroll
        for (int nn = 0; nn < 4; nn++) {
            b8v bk = *(const b8v*)&kl[nn * 16 + r][kt * 32 + q * 8];
            sc[nn] = __builtin_amdgcn_mfma_f32_16x16x32_bf16(aq, bk, sc[nn], 0, 0, 0);
        }
    }
    // softmax over t: lane holds rows s=w*16+q*4+j, cols t=nn*16+r
    #pragma unroll
    for (int j = 0; j < 4; j++) {
        float m = fmaxf(fmaxf(sc[0][j], sc[1][j]), fmaxf(sc[2][j], sc[3][j]));
        #pragma unroll
        for (int d = 1; d < 16; d <<= 1) m = fmaxf(m, __shfl_xor(m, d));
        float p[4], sum = 0.f;
        #pragma unroll
        for (int nn = 0; nn < 4; nn++) {
            p[nn] = __expf((sc[nn][j] - m) * 0.125f);   // fold 1/sqrt(64)
            sum += p[nn];
        }
        #pragma unroll
        for (int d = 1; d < 16; d <<= 1) sum += __shfl_xor(sum, d);
        const float inv = 1.f / sum;
        #pragma unroll
        for (int nn = 0; nn < 4; nn++)
            pl[w * 16 + q * 4 + j][nn * 16 + r] = f2bf(p[nn] * inv);
    }
    __syncthreads();
    f32x4 oc[4] = {};
    #pragma unroll
    for (int kt = 0; kt < 2; ++kt) {
        b8v ap = *(const b8v*)&pl[w * 16 + r][kt * 32 + q * 8];
        #pragma unroll
        for (int nn = 0; nn < 4; nn++) {
            b8v bv = *(const b8v*)&vt[nn * 16 + r][kt * 32 + q * 8];
            oc[nn] = __builtin_amdgcn_mfma_f32_16x16x32_bf16(ap, bv, oc[nn], 0, 0, 0);
        }
    }
    #pragma unroll
    for (int nn = 0; nn < 4; nn++)
        #pragma unroll
        for (int j = 0; j < 4; j++) {
            const int s = w * 16 + q * 4 + j;
            o[(size_t)(s * B_ + b) * 1024 + h * 64 + nn * 16 + r] = f2bf(oc[nn][j]);
        }
}

// ---------------------------------------------------------------- LayerNorm
template<int OUTP>
__global__ __launch_bounds__(256)
void ln_k(const short* __restrict__ xin, const short* __restrict__ resid,
          const float* __restrict__ gam, const float* __restrict__ bet,
          short* __restrict__ outb, float* __restrict__ outf)
{
    const int row = blockIdx.x, tid = threadIdx.x;
    const s4v xs = ((const s4v*)(xin   + (size_t)row * 1024))[tid];
    const s4v rs = ((const s4v*)(resid + (size_t)row * 1024))[tid];
    float v[4], s = 0.f, s2 = 0.f;
    #pragma unroll
    for (int i = 0; i < 4; i++) {
        v[i] = bf2f(xs[i]) + bf2f(rs[i]);
        s += v[i]; s2 += v[i] * v[i];
    }
    #pragma unroll
    for (int d = 1; d < 64; d <<= 1) { s += __shfl_xor(s, d); s2 += __shfl_xor(s2, d); }
    __shared__ float red[8];
    const int wid = tid >> 6, lane = tid & 63;
    if (lane == 0) { red[wid] = s; red[4 + wid] = s2; }
    __syncthreads();
    s  = red[0] + red[1] + red[2] + red[3];
    s2 = red[4] + red[5] + red[6] + red[7];
    const float mean = s * (1.f / 1024.f);
    const float var  = s2 * (1.f / 1024.f) - mean * mean;
    const float rstd = rsqrtf(var + 1e-5f);
    const f32v4 g4 = ((const f32v4*)gam)[tid];
    const f32v4 b4 = ((const f32v4*)bet)[tid];
    if (OUTP == 0) {
        s4v ov;
        #pragma unroll
        for (int i = 0; i < 4; i++) ov[i] = f2bf((v[i] - mean) * rstd * g4[i] + b4[i]);
        ((s4v*)(outb + (size_t)row * 1024))[tid] = ov;
    } else {
        f32v4 ov;
        #pragma unroll
        for (int i = 0; i < 4; i++) ov[i] = (v[i] - mean) * rstd * g4[i] + b4[i];
        ((f32v4*)(outf + (size_t)((row & 255) * 64 + (row >> 8)) * 1024))[tid] = ov;
    }
}

// ---------------------------------------------------------------- gate
__global__ __launch_bounds__(256)
void gate_k(const float* __restrict__ cat, const float* __restrict__ W1,
            const float* __restrict__ b1, const float* __restrict__ W2,
            const float* __restrict__ b2, float* __restrict__ coef,
            float* __restrict__ outscalar)
{
    const int b = blockIdx.x, tid = threadIdx.x;
    __shared__ float g[2048];
    __shared__ float h[256];
    __shared__ float lg[5];
    for (int i = tid; i < 1024; i += 256) {
        g[i]        = cat[(size_t)b * 1024 + i];             // prop (s=0)
        g[1024 + i] = cat[(size_t)(B_ + b) * 1024 + i];      // refe (s=1)
    }
    __syncthreads();
    float a = b1[tid];
    for (int d = 0; d < 2048; ++d) a += g[d] * W1[(size_t)d * 256 + tid];
    h[tid] = fmaxf(a, 0.f);
    __syncthreads();
    if (tid < 5) {
        float l = b2[tid];
        for (int i = 0; i < 256; ++i) l += h[i] * W2[i * 5 + tid];
        lg[tid] = l;
    }
    __syncthreads();
    if (tid == 0) {
        float l[5]; int ks = 0; float mx;
        #pragma unroll
        for (int j = 0; j < 5; j++) l[j] = lg[j];
        mx = l[0];
        for (int j = 1; j < 5; j++) if (l[j] > mx) { mx = l[j]; ks = j; }
        float e[5], se = 0.f;
        #pragma unroll
        for (int j = 0; j < 5; j++) { e[j] = expf(l[j] - mx); se += e[j]; }
        for (int ee = 0; ee < 4; ++ee) {
            float wv = 0.f;
            for (int j = ee + 1; j < 5; ++j) wv += e[j];
            coef[ee * B_ + b] = (ks >= ee + 1) ? (wv / se) : 0.f;
        }
    }
    if (b == 0 && tid == 0) outscalar[0] = 0.f;   // tuple's second output
}

// ---------------------------------------------------------------- converters
// fp32 [K][N] -> bf16 [N][K]
__global__ __launch_bounds__(256)
void tconv_k(const float* __restrict__ in, short* __restrict__ out, int K, int N)
{
    __shared__ float t[32][33];
    const int bx = blockIdx.x, by = blockIdx.y;
    const int tx = threadIdx.x & 31, ty = threadIdx.x >> 5;
    #pragma unroll
    for (int i = 0; i < 32; i += 8)
        t[ty + i][tx] = in[(size_t)(by * 32 + ty + i) * N + bx * 32 + tx];
    __syncthreads();
    #pragma unroll
    for (int i = 0; i < 32; i += 8)
        out[(size_t)(bx * 32 + ty + i) * K + by * 32 + tx] = f2bf(t[tx][ty + i]);
}

__global__ __launch_bounds__(256)
void f2bf_k(const float* __restrict__ in, short* __restrict__ out, int n4)
{
    const int i = blockIdx.x * 256 + threadIdx.x;
    if (i < n4) {
        const f32v4 v = ((const f32v4*)in)[i];
        s4v o;
        #pragma unroll
        for (int j = 0; j < 4; j++) o[j] = f2bf(v[j]);
        ((s4v*)out)[i] = o;
    }
}

// diagnostic: absmax ~= ws_size tells us the workspace was too small
__global__ void diag_k(float* out, float val) { out[0] = val; }

// ---------------------------------------------------------------- launch
extern "C" void kernel_launch(void* const* d_in, const int* in_sizes, int n_in,
                              void* d_out, int out_size, void* d_ws, size_t ws_size,
                              hipStream_t stream)
{
    const float* cat   = (const float*)d_in[0];
    const float* gW1   = (const float*)d_in[1];
    const float* gb1   = (const float*)d_in[2];
    const float* gW2   = (const float*)d_in[3];
    const float* gb2   = (const float*)d_in[4];
    const float* zW    = (const float*)d_in[29];
    const float* zb    = (const float*)d_in[30];
    const float* outW  = (const float*)d_in[31];
    const float* outb_ = (const float*)d_in[32];

    char* w = (char*)d_ws;
    size_t off = 0;
    auto alloc = [&](size_t bytes) { void* p = w + off; off = (off + bytes + 255) & ~(size_t)255; return p; };
    // per-layer weight staging (reused across the 5 encoder layers)
    short* wq    = (short*)alloc((size_t)3072 * 1024 * 2);
    short* wo    = (short*)alloc((size_t)1024 * 1024 * 2);
    short* w1t   = (short*)alloc((size_t)4096 * 1024 * 2);
    short* w2t   = (short*)alloc((size_t)1024 * 4096 * 2);
    short* wz    = (short*)alloc((size_t)1024 * 1024 * 2);
    short* outWT = (short*)alloc((size_t)512 * 1024 * 2);
    short* catbf = (short*)alloc((size_t)M_TOK * 1024 * 2);
    short* big   = (short*)alloc((size_t)M_TOK * 4096 * 2);   // qkv (100MB) / h1 (134MB)
    short* tmp   = (short*)alloc((size_t)M_TOK * 1024 * 2);
    short* x1    = (short*)alloc((size_t)M_TOK * 1024 * 2);
    float* acc   = (float*)alloc((size_t)M_TOK * 1024 * 4);
    float* coef  = (float*)alloc((size_t)4 * 256 * 4);
    // attn-out / x2 aliases big's tail (lifetimes verified round 3)
    short* attno = big + (size_t)M_TOK * 3072;
    (void)n_in; (void)in_sizes;

    if (off > ws_size) {   // workspace too small: fail cleanly + report size
        hipMemsetAsync(d_out, 0, (size_t)out_size * 4, stream);
        diag_k<<<1, 1, 0, stream>>>((float*)d_out, (float)ws_size);
        return;
    }

    // one-time conversions
    tconv_k<<<dim3(16, 32), 256, 0, stream>>>(outW, outWT, 1024, 512);
    f2bf_k<<<16384, 256, 0, stream>>>(cat, catbf, M_TOK * 1024 / 4);

    // gate (also writes the tuple's scalar 0.0)
    gate_k<<<B_, 256, 0, stream>>>(cat, gW1, gb1, gW2, gb2, coef,
                                   (float*)d_out + (size_t)M_TOK * OUT_);

    auto encoder = [&](int enc, bool base) {
        const int e = enc - 1;
        const float *Wq_f, *Wo_f, *W1_f, *W2_f;
        const float *bq, *bo, *l1g, *l1b, *bf1, *bf2, *l2g, *l2b;
        if (base) {
            Wq_f = (const float*)d_in[5];  W1_f = (const float*)d_in[11];
            Wo_f = (const float*)d_in[7];  W2_f = (const float*)d_in[13];
            bq  = (const float*)d_in[6];  bo  = (const float*)d_in[8];
            l1g = (const float*)d_in[9];  l1b = (const float*)d_in[10];
            bf1 = (const float*)d_in[12]; bf2 = (const float*)d_in[14];
            l2g = (const float*)d_in[15]; l2b = (const float*)d_in[16];
        } else {
            Wq_f = (const float*)d_in[17] + (size_t)e * 1024 * 3072;
            Wo_f = (const float*)d_in[19] + (size_t)e * 1024 * 1024;
            W1_f = (const float*)d_in[23] + (size_t)e * 1024 * 4096;
            W2_f = (const float*)d_in[25] + (size_t)e * 4096 * 1024;
            bq  = (const float*)d_in[18] + (size_t)e * 3072;
            bo  = (const float*)d_in[20] + (size_t)e * 1024;
            l1g = (const float*)d_in[21] + (size_t)e * 1024;
            l1b = (const float*)d_in[22] + (size_t)e * 1024;
            bf1 = (const float*)d_in[24] + (size_t)e * 4096;
            bf2 = (const float*)d_in[26] + (size_t)e * 1024;
            l2g = (const float*)d_in[27] + (size_t)e * 1024;
            l2b = (const float*)d_in[28] + (size_t)e * 1024;
        }
        // per-layer weight conversion into the shared staging buffers
        tconv_k<<<dim3(96, 32),  256, 0, stream>>>(Wq_f, wq,  1024, 3072);
        tconv_k<<<dim3(32, 32),  256, 0, stream>>>(Wo_f, wo,  1024, 1024);
        tconv_k<<<dim3(128, 32), 256, 0, stream>>>(W1_f, w1t, 1024, 4096);
        tconv_k<<<dim3(32, 128), 256, 0, stream>>>(W2_f, w2t, 4096, 1024);
        if (!base)
            tconv_k<<<dim3(32, 32), 256, 0, stream>>>(zW + (size_t)e * 1024 * 1024, wz, 1024, 1024);

        gemm_k<0><<<dim3(24, 128), 256, 0, stream>>>(catbf, wq, bq, big, nullptr,
                                                     M_TOK, 3072, 1024, nullptr, nullptr);
        attn_k<<<B_ * 16, 256, 0, stream>>>(big, attno);
        gemm_k<0><<<dim3(8, 128), 256, 0, stream>>>(attno, wo, bo, tmp, nullptr,
                                                    M_TOK, 1024, 1024, nullptr, nullptr);
        ln_k<0><<<M_TOK, 256, 0, stream>>>(tmp, catbf, l1g, l1b, x1, nullptr);
        gemm_k<1><<<dim3(32, 128), 256, 0, stream>>>(x1, w1t, bf1, big, nullptr,
                                                     M_TOK, 4096, 1024, nullptr, nullptr);
        gemm_k<0><<<dim3(8, 128), 256, 0, stream>>>(big, w2t, bf2, tmp, nullptr,
                                                    M_TOK, 1024, 4096, nullptr, nullptr);
        if (base) {
            ln_k<1><<<M_TOK, 256, 0, stream>>>(tmp, x1, l2g, l2b, nullptr, acc);
        } else {
            ln_k<0><<<M_TOK, 256, 0, stream>>>(tmp, x1, l2g, l2b, attno, nullptr);  // x2
            gemm_k<2><<<dim3(8, 128), 256, 0, stream>>>(attno, wz,
                                                        zb + (size_t)e * 1024, nullptr, nullptr,
                                                        M_TOK, 1024, 1024, coef + e * 256, acc);
        }
    };
    encoder(0, true);
    for (int e = 0; e < 4; ++e) encoder(e + 1, false);

    // final projection: out[b,s,:] = acc_row(b*64+s) @ out_W + out_b
    f2bf_k<<<16384, 256, 0, stream>>>(acc, x1, M_TOK * 1024 / 4);
    gemm_k<3><<<dim3(4, 128), 256, 0, stream>>>(x1, outWT, outb_, nullptr, (float*)d_out,
                                                M_TOK, 512, 1024, nullptr, nullptr);
}

// Round 8
// 3317.688 us; speedup vs baseline: 1.3232x; 1.2732x over previous
//
#include <hip/hip_runtime.h>

// ---------------------------------------------------------------- types
typedef __bf16  b8v   __attribute__((ext_vector_type(8)));
typedef float   f32x4 __attribute__((ext_vector_type(4)));
typedef float   f32v4 __attribute__((ext_vector_type(4)));
typedef short   s4v   __attribute__((ext_vector_type(4)));
typedef short   s8v   __attribute__((ext_vector_type(8)));
typedef int     i4v   __attribute__((ext_vector_type(4)));

#define M_TOK 16384   // S*B
#define S_    64
#define B_    256
#define D_    1024
#define F_    4096
#define E_    4
#define OUT_  512

__device__ __forceinline__ short f2bf(float f) {
    unsigned u = __builtin_bit_cast(unsigned, f);
    u += 0x7fffu + ((u >> 16) & 1u);          // RNE
    return (short)(u >> 16);
}
__device__ __forceinline__ float bf2f(short s) {
    unsigned u = ((unsigned)(unsigned short)s) << 16;
    return __builtin_bit_cast(float, u);
}
__device__ __forceinline__ void gll16(const short* g, short* l) {
    __builtin_amdgcn_global_load_lds(
        (__attribute__((address_space(1))) void*)(void*)const_cast<short*>(g),
        (__attribute__((address_space(3))) void*)l, 16, 0, 0);
}

// ---------------------------------------------------------------- GEMM (256^2 phase-split)
// C[M,N] = A[M,K](bf16) @ Wt[N,K](bf16) + bias.
// EPI: 0 bf16 out, 1 relu->bf16, 2 MoE acc[perm]+=coef*val, 3 fp32 out.
//
// Template: 256x256 tile, BK=64, 8 waves (2Mx4N), each wave owns 128x64
// (M_rep=8, N_rep=4 fragments of 16x16x32). LDS 128KB = 2 bufs x (A+B tile).
// T2 swizzle: LDS granule (row, gc) holds global data (row, gc^(row&7));
//   staged by pre-swizzling the per-lane GLOBAL address (LDS dest stays
//   linear base+lane*16 as HW requires), read back with the same XOR
//   (involution => both-sides-consistent, rule #21).
// T3/T4: 4 MFMA quadrant-phases per K-tile with raw s_barrier; next-next
//   tile staged after the tile's last read-barrier; counted vmcnt(8) keeps
//   the NEXT tile's 8 loads in flight across the barrier (never drains).
//   Proof: queue = [t+1's 8, t+2's 8]; vmcnt(8) retires exactly t+1's.
// T5: setprio(1) around each MFMA cluster.
template<int EPI>
__global__ __launch_bounds__(512, 2)
void gemm2_k(const short* __restrict__ A, const short* __restrict__ Bt,
             const float* __restrict__ bias,
             short* __restrict__ outb, float* __restrict__ outf,
             int M, int N, int K,
             const float* __restrict__ coef, float* __restrict__ accp)
{
    __shared__ __align__(16) short lds[2][2][256 * 64];   // [buf][A|B][row*64+col]
    const int tid  = threadIdx.x;
    const int lane = tid & 63, wid = tid >> 6;
    const int wm = wid >> 2, wn = wid & 3;
    const int r = lane & 15, q = lane >> 4;

    // T1: XCD-aware chunked block remap (bm-major chunks per XCD).
    const int nbn = gridDim.x;
    int dd = blockIdx.y * nbn + blockIdx.x;
    const int nwg = nbn * (int)gridDim.y;
    if ((nwg & 7) == 0) { const int cpx = nwg >> 3; dd = (dd & 7) * cpx + (dd >> 3); }
    const int bn = dd % nbn, bm = dd / nbn;

    // staging: 4 rounds per matrix; round j covers granules G=j*512+wid*64+lane
    // (G = row*8+gc, row=G>>3, gc=G&7). Source pre-swizzled: gc' = gc^(row&7).
    size_t aoff[4], boff[4];
    #pragma unroll
    for (int j = 0; j < 4; ++j) {
        const int G = j * 512 + wid * 64 + lane;
        const int row = G >> 3, gc = G & 7;
        const int gcs = gc ^ (row & 7);
        aoff[j] = (size_t)(bm * 256 + row) * K * 2 + (size_t)gcs * 16;
        boff[j] = (size_t)(bn * 256 + row) * K * 2 + (size_t)gcs * 16;
    }
    auto stage = [&](int c, int t) {
        const size_t co = (size_t)t * 128;
        #pragma unroll
        for (int j = 0; j < 4; ++j)
            gll16((const short*)((const char*)A + aoff[j] + co),
                  &lds[c][0][(j * 512 + wid * 64 + lane) * 8]);
        #pragma unroll
        for (int j = 0; j < 4; ++j)
            gll16((const short*)((const char*)Bt + boff[j] + co),
                  &lds[c][1][(j * 512 + wid * 64 + lane) * 8]);
    };

    // swizzled fragment reads: row&7 == r&7 for every frag (frag row step 16)
    const int rx = r & 7;
    const int arb = (wm * 128 + r) * 8;   // + mf*128 granules
    const int brb = (wn * 64 + r) * 8;    // + nf*128 granules
    auto lda = [&](int c, int mf, int ks) {
        return *(const b8v*)&lds[c][0][(arb + mf * 128 + (((ks << 2) + q) ^ rx)) * 8];
    };
    auto ldb = [&](int c, int nf, int ks) {
        return *(const b8v*)&lds[c][1][(brb + nf * 128 + (((ks << 2) + q) ^ rx)) * 8];
    };

    f32x4 acc[8][4] = {};
    const int NT = K >> 6;
    stage(0, 0);
    stage(1, 1);
    asm volatile("s_waitcnt vmcnt(8)" ::: "memory");   // tile0 landed; tile1 in flight
    __builtin_amdgcn_s_barrier();
    asm volatile("" ::: "memory");

    int c = 0;
    for (int t = 0; t < NT; ++t) {
        b8v af[4][2], bf[2][2];
        // ---- P1: quadrant (mh=0, nh=0)
        #pragma unroll
        for (int i = 0; i < 4; ++i) { af[i][0] = lda(c, i, 0); af[i][1] = lda(c, i, 1); }
        #pragma unroll
        for (int j2 = 0; j2 < 2; ++j2) { bf[j2][0] = ldb(c, j2, 0); bf[j2][1] = ldb(c, j2, 1); }
        __builtin_amdgcn_s_setprio(1);
        #pragma unroll
        for (int i = 0; i < 4; ++i)
            #pragma unroll
            for (int j2 = 0; j2 < 2; ++j2)
                #pragma unroll
                for (int ks = 0; ks < 2; ++ks)
                    acc[i][j2] = __builtin_amdgcn_mfma_f32_16x16x32_bf16(af[i][ks], bf[j2][ks], acc[i][j2], 0, 0, 0);
        __builtin_amdgcn_s_setprio(0);
        __builtin_amdgcn_s_barrier();
        // ---- P2: quadrant (0,1): reuse A, load B nf=2,3
        #pragma unroll
        for (int j2 = 0; j2 < 2; ++j2) { bf[j2][0] = ldb(c, 2 + j2, 0); bf[j2][1] = ldb(c, 2 + j2, 1); }
        __builtin_amdgcn_s_setprio(1);
        #pragma unroll
        for (int i = 0; i < 4; ++i)
            #pragma unroll
            for (int j2 = 0; j2 < 2; ++j2)
                #pragma unroll
                for (int ks = 0; ks < 2; ++ks)
                    acc[i][2 + j2] = __builtin_amdgcn_mfma_f32_16x16x32_bf16(af[i][ks], bf[j2][ks], acc[i][2 + j2], 0, 0, 0);
        __builtin_amdgcn_s_setprio(0);
        __builtin_amdgcn_s_barrier();
        // ---- P3: quadrant (1,1): load A mf=4..7, reuse B nf=2,3
        #pragma unroll
        for (int i = 0; i < 4; ++i) { af[i][0] = lda(c, 4 + i, 0); af[i][1] = lda(c, 4 + i, 1); }
        __builtin_amdgcn_s_setprio(1);
        #pragma unroll
        for (int i = 0; i < 4; ++i)
            #pragma unroll
            for (int j2 = 0; j2 < 2; ++j2)
                #pragma unroll
                for (int ks = 0; ks < 2; ++ks)
                    acc[4 + i][2 + j2] = __builtin_amdgcn_mfma_f32_16x16x32_bf16(af[i][ks], bf[j2][ks], acc[4 + i][2 + j2], 0, 0, 0);
        __builtin_amdgcn_s_setprio(0);
        __builtin_amdgcn_s_barrier();
        // ---- P4: quadrant (1,0): reload B nf=0,1
        #pragma unroll
        for (int j2 = 0; j2 < 2; ++j2) { bf[j2][0] = ldb(c, j2, 0); bf[j2][1] = ldb(c, j2, 1); }
        __builtin_amdgcn_s_setprio(1);
        #pragma unroll
        for (int i = 0; i < 4; ++i)
            #pragma unroll
            for (int j2 = 0; j2 < 2; ++j2)
                #pragma unroll
                for (int ks = 0; ks < 2; ++ks)
                    acc[4 + i][j2] = __builtin_amdgcn_mfma_f32_16x16x32_bf16(af[i][ks], bf[j2][ks], acc[4 + i][j2], 0, 0, 0);
        __builtin_amdgcn_s_setprio(0);
        // ---- end of tile t: all reads of buf c complete (data-dep lgkm waits done)
        asm volatile("" ::: "memory");
        __builtin_amdgcn_s_barrier();                  // cross-wave: buf c free
        if (t + 2 < NT) {
            stage(c, t + 2);                           // overwrite freed buf
            asm volatile("s_waitcnt vmcnt(8)" ::: "memory");  // t+1 landed; t+2 in flight
        } else {
            asm volatile("s_waitcnt vmcnt(0)" ::: "memory");  // tail: drain last tile
        }
        __builtin_amdgcn_s_barrier();                  // cross-wave: buf c^1 ready
        asm volatile("" ::: "memory");
        c ^= 1;
    }

    // epilogue: C/D frag layout col=lane&15 (=r), row=(lane>>4)*4+reg (m89-verified)
    float bv[4];
    #pragma unroll
    for (int nf = 0; nf < 4; ++nf) bv[nf] = bias[bn * 256 + wn * 64 + nf * 16 + r];
    #pragma unroll
    for (int mf = 0; mf < 8; ++mf) {
        const int row0 = bm * 256 + wm * 128 + mf * 16 + q * 4;
        #pragma unroll
        for (int nf = 0; nf < 4; ++nf) {
            const int col = bn * 256 + wn * 64 + nf * 16 + r;
            #pragma unroll
            for (int jj = 0; jj < 4; ++jj) {
                const int row = row0 + jj;
                float v = acc[mf][nf][jj] + bv[nf];
                if (EPI == 1) v = fmaxf(v, 0.f);
                if (EPI <= 1) {
                    outb[(size_t)row * N + col] = f2bf(v);
                } else if (EPI == 2) {
                    const int b = row & 255, s = row >> 8;   // row = s*256+b
                    accp[(size_t)(b * 64 + s) * N + col] += coef[b] * v;
                } else {
                    outf[(size_t)row * N + col] = v;
                }
            }
        }
    }
}

// ---------------------------------------------------------------- attention
__global__ __launch_bounds__(256)
void attn_k(const short* __restrict__ qkv, short* __restrict__ o)
{
    __shared__ __align__(16) short ql[64][72], kl[64][72], vt[64][72], pl[64][72];
    const int bh = blockIdx.x;
    const int b = bh >> 4, h = bh & 15;
    const int tid = threadIdx.x;
    for (int c = tid; c < 512; c += 256) {
        const int s = c >> 3, d0 = (c & 7) * 8;
        const short* gp = qkv + (size_t)(s * B_ + b) * 3072 + h * 64 + d0;
        *(i4v*)&ql[s][d0] = *(const i4v*)gp;
        *(i4v*)&kl[s][d0] = *(const i4v*)(gp + 1024);
        s8v vv = *(const s8v*)(gp + 2048);
        #pragma unroll
        for (int i = 0; i < 8; i++) vt[d0 + i][s] = vv[i];   // V^T: vt[d][t]
    }
    __syncthreads();
    const int lane = tid & 63, w = tid >> 6;
    const int r = lane & 15, q = lane >> 4;

    f32x4 sc[4] = {};
    #pragma unroll
    for (int kt = 0; kt < 2; ++kt) {
        b8v aq = *(const b8v*)&ql[w * 16 + r][kt * 32 + q * 8];
        #pragma unroll
        for (int nn = 0; nn < 4; nn++) {
            b8v bk = *(const b8v*)&kl[nn * 16 + r][kt * 32 + q * 8];
            sc[nn] = __builtin_amdgcn_mfma_f32_16x16x32_bf16(aq, bk, sc[nn], 0, 0, 0);
        }
    }
    // softmax over t: lane holds rows s=w*16+q*4+j, cols t=nn*16+r
    #pragma unroll
    for (int j = 0; j < 4; j++) {
        float m = fmaxf(fmaxf(sc[0][j], sc[1][j]), fmaxf(sc[2][j], sc[3][j]));
        #pragma unroll
        for (int d = 1; d < 16; d <<= 1) m = fmaxf(m, __shfl_xor(m, d));
        float p[4], sum = 0.f;
        #pragma unroll
        for (int nn = 0; nn < 4; nn++) {
            p[nn] = __expf((sc[nn][j] - m) * 0.125f);   // fold 1/sqrt(64)
            sum += p[nn];
        }
        #pragma unroll
        for (int d = 1; d < 16; d <<= 1) sum += __shfl_xor(sum, d);
        const float inv = 1.f / sum;
        #pragma unroll
        for (int nn = 0; nn < 4; nn++)
            pl[w * 16 + q * 4 + j][nn * 16 + r] = f2bf(p[nn] * inv);
    }
    __syncthreads();
    f32x4 oc[4] = {};
    #pragma unroll
    for (int kt = 0; kt < 2; ++kt) {
        b8v ap = *(const b8v*)&pl[w * 16 + r][kt * 32 + q * 8];
        #pragma unroll
        for (int nn = 0; nn < 4; nn++) {
            b8v bv = *(const b8v*)&vt[nn * 16 + r][kt * 32 + q * 8];
            oc[nn] = __builtin_amdgcn_mfma_f32_16x16x32_bf16(ap, bv, oc[nn], 0, 0, 0);
        }
    }
    #pragma unroll
    for (int nn = 0; nn < 4; nn++)
        #pragma unroll
        for (int j = 0; j < 4; j++) {
            const int s = w * 16 + q * 4 + j;
            o[(size_t)(s * B_ + b) * 1024 + h * 64 + nn * 16 + r] = f2bf(oc[nn][j]);
        }
}

// ---------------------------------------------------------------- LayerNorm
template<int OUTP>
__global__ __launch_bounds__(256)
void ln_k(const short* __restrict__ xin, const short* __restrict__ resid,
          const float* __restrict__ gam, const float* __restrict__ bet,
          short* __restrict__ outb, float* __restrict__ outf)
{
    const int row = blockIdx.x, tid = threadIdx.x;
    const s4v xs = ((const s4v*)(xin   + (size_t)row * 1024))[tid];
    const s4v rs = ((const s4v*)(resid + (size_t)row * 1024))[tid];
    float v[4], s = 0.f, s2 = 0.f;
    #pragma unroll
    for (int i = 0; i < 4; i++) {
        v[i] = bf2f(xs[i]) + bf2f(rs[i]);
        s += v[i]; s2 += v[i] * v[i];
    }
    #pragma unroll
    for (int d = 1; d < 64; d <<= 1) { s += __shfl_xor(s, d); s2 += __shfl_xor(s2, d); }
    __shared__ float red[8];
    const int wid = tid >> 6, lane = tid & 63;
    if (lane == 0) { red[wid] = s; red[4 + wid] = s2; }
    __syncthreads();
    s  = red[0] + red[1] + red[2] + red[3];
    s2 = red[4] + red[5] + red[6] + red[7];
    const float mean = s * (1.f / 1024.f);
    const float var  = s2 * (1.f / 1024.f) - mean * mean;
    const float rstd = rsqrtf(var + 1e-5f);
    const f32v4 g4 = ((const f32v4*)gam)[tid];
    const f32v4 b4 = ((const f32v4*)bet)[tid];
    if (OUTP == 0) {
        s4v ov;
        #pragma unroll
        for (int i = 0; i < 4; i++) ov[i] = f2bf((v[i] - mean) * rstd * g4[i] + b4[i]);
        ((s4v*)(outb + (size_t)row * 1024))[tid] = ov;
    } else {
        f32v4 ov;
        #pragma unroll
        for (int i = 0; i < 4; i++) ov[i] = (v[i] - mean) * rstd * g4[i] + b4[i];
        ((f32v4*)(outf + (size_t)((row & 255) * 64 + (row >> 8)) * 1024))[tid] = ov;
    }
}

// ---------------------------------------------------------------- gate
__global__ __launch_bounds__(256)
void gate_k(const float* __restrict__ cat, const float* __restrict__ W1,
            const float* __restrict__ b1, const float* __restrict__ W2,
            const float* __restrict__ b2, float* __restrict__ coef,
            float* __restrict__ outscalar)
{
    const int b = blockIdx.x, tid = threadIdx.x;
    __shared__ float g[2048];
    __shared__ float h[256];
    __shared__ float lg[5];
    for (int i = tid; i < 1024; i += 256) {
        g[i]        = cat[(size_t)b * 1024 + i];             // prop (s=0)
        g[1024 + i] = cat[(size_t)(B_ + b) * 1024 + i];      // refe (s=1)
    }
    __syncthreads();
    float a = b1[tid];
    for (int d = 0; d < 2048; ++d) a += g[d] * W1[(size_t)d * 256 + tid];
    h[tid] = fmaxf(a, 0.f);
    __syncthreads();
    if (tid < 5) {
        float l = b2[tid];
        for (int i = 0; i < 256; ++i) l += h[i] * W2[i * 5 + tid];
        lg[tid] = l;
    }
    __syncthreads();
    if (tid == 0) {
        float l[5]; int ks = 0; float mx;
        #pragma unroll
        for (int j = 0; j < 5; j++) l[j] = lg[j];
        mx = l[0];
        for (int j = 1; j < 5; j++) if (l[j] > mx) { mx = l[j]; ks = j; }
        float e[5], se = 0.f;
        #pragma unroll
        for (int j = 0; j < 5; j++) { e[j] = expf(l[j] - mx); se += e[j]; }
        for (int ee = 0; ee < 4; ++ee) {
            float wv = 0.f;
            for (int j = ee + 1; j < 5; ++j) wv += e[j];
            coef[ee * B_ + b] = (ks >= ee + 1) ? (wv / se) : 0.f;
        }
    }
    if (b == 0 && tid == 0) outscalar[0] = 0.f;   // tuple's second output
}

// ---------------------------------------------------------------- converters
// fp32 [K][N] -> bf16 [N][K]
__global__ __launch_bounds__(256)
void tconv_k(const float* __restrict__ in, short* __restrict__ out, int K, int N)
{
    __shared__ float t[32][33];
    const int bx = blockIdx.x, by = blockIdx.y;
    const int tx = threadIdx.x & 31, ty = threadIdx.x >> 5;
    #pragma unroll
    for (int i = 0; i < 32; i += 8)
        t[ty + i][tx] = in[(size_t)(by * 32 + ty + i) * N + bx * 32 + tx];
    __syncthreads();
    #pragma unroll
    for (int i = 0; i < 32; i += 8)
        out[(size_t)(bx * 32 + ty + i) * K + by * 32 + tx] = f2bf(t[tx][ty + i]);
}

__global__ __launch_bounds__(256)
void f2bf_k(const float* __restrict__ in, short* __restrict__ out, int n4)
{
    const int i = blockIdx.x * 256 + threadIdx.x;
    if (i < n4) {
        const f32v4 v = ((const f32v4*)in)[i];
        s4v o;
        #pragma unroll
        for (int j = 0; j < 4; j++) o[j] = f2bf(v[j]);
        ((s4v*)out)[i] = o;
    }
}

// diagnostic: absmax ~= ws_size tells us the workspace was too small
__global__ void diag_k(float* out, float val) { out[0] = val; }

// ---------------------------------------------------------------- launch
extern "C" void kernel_launch(void* const* d_in, const int* in_sizes, int n_in,
                              void* d_out, int out_size, void* d_ws, size_t ws_size,
                              hipStream_t stream)
{
    const float* cat   = (const float*)d_in[0];
    const float* gW1   = (const float*)d_in[1];
    const float* gb1   = (const float*)d_in[2];
    const float* gW2   = (const float*)d_in[3];
    const float* gb2   = (const float*)d_in[4];
    const float* zW    = (const float*)d_in[29];
    const float* zb    = (const float*)d_in[30];
    const float* outW  = (const float*)d_in[31];
    const float* outb_ = (const float*)d_in[32];

    char* w = (char*)d_ws;
    size_t off = 0;
    auto alloc = [&](size_t bytes) { void* p = w + off; off = (off + bytes + 255) & ~(size_t)255; return p; };
    // per-layer weight staging (reused across the 5 encoder layers)
    short* wq    = (short*)alloc((size_t)3072 * 1024 * 2);
    short* wo    = (short*)alloc((size_t)1024 * 1024 * 2);
    short* w1t   = (short*)alloc((size_t)4096 * 1024 * 2);
    short* w2t   = (short*)alloc((size_t)1024 * 4096 * 2);
    short* wz    = (short*)alloc((size_t)1024 * 1024 * 2);
    short* outWT = (short*)alloc((size_t)512 * 1024 * 2);
    short* catbf = (short*)alloc((size_t)M_TOK * 1024 * 2);
    short* big   = (short*)alloc((size_t)M_TOK * 4096 * 2);   // qkv (100MB) / h1 (134MB)
    short* tmp   = (short*)alloc((size_t)M_TOK * 1024 * 2);
    short* x1    = (short*)alloc((size_t)M_TOK * 1024 * 2);
    float* acc   = (float*)alloc((size_t)M_TOK * 1024 * 4);
    float* coef  = (float*)alloc((size_t)4 * 256 * 4);
    // attn-out / x2 aliases big's tail (lifetimes verified round 3)
    short* attno = big + (size_t)M_TOK * 3072;
    (void)n_in; (void)in_sizes;

    if (off > ws_size) {   // workspace too small: fail cleanly + report size
        hipMemsetAsync(d_out, 0, (size_t)out_size * 4, stream);
        diag_k<<<1, 1, 0, stream>>>((float*)d_out, (float)ws_size);
        return;
    }

    // one-time conversions
    tconv_k<<<dim3(16, 32), 256, 0, stream>>>(outW, outWT, 1024, 512);
    f2bf_k<<<16384, 256, 0, stream>>>(cat, catbf, M_TOK * 1024 / 4);

    // gate (also writes the tuple's scalar 0.0)
    gate_k<<<B_, 256, 0, stream>>>(cat, gW1, gb1, gW2, gb2, coef,
                                   (float*)d_out + (size_t)M_TOK * OUT_);

    auto encoder = [&](int enc, bool base) {
        const int e = enc - 1;
        const float *Wq_f, *Wo_f, *W1_f, *W2_f;
        const float *bq, *bo, *l1g, *l1b, *bf1, *bf2, *l2g, *l2b;
        if (base) {
            Wq_f = (const float*)d_in[5];  W1_f = (const float*)d_in[11];
            Wo_f = (const float*)d_in[7];  W2_f = (const float*)d_in[13];
            bq  = (const float*)d_in[6];  bo  = (const float*)d_in[8];
            l1g = (const float*)d_in[9];  l1b = (const float*)d_in[10];
            bf1 = (const float*)d_in[12]; bf2 = (const float*)d_in[14];
            l2g = (const float*)d_in[15]; l2b = (const float*)d_in[16];
        } else {
            Wq_f = (const float*)d_in[17] + (size_t)e * 1024 * 3072;
            Wo_f = (const float*)d_in[19] + (size_t)e * 1024 * 1024;
            W1_f = (const float*)d_in[23] + (size_t)e * 1024 * 4096;
            W2_f = (const float*)d_in[25] + (size_t)e * 4096 * 1024;
            bq  = (const float*)d_in[18] + (size_t)e * 3072;
            bo  = (const float*)d_in[20] + (size_t)e * 1024;
            l1g = (const float*)d_in[21] + (size_t)e * 1024;
            l1b = (const float*)d_in[22] + (size_t)e * 1024;
            bf1 = (const float*)d_in[24] + (size_t)e * 4096;
            bf2 = (const float*)d_in[26] + (size_t)e * 1024;
            l2g = (const float*)d_in[27] + (size_t)e * 1024;
            l2b = (const float*)d_in[28] + (size_t)e * 1024;
        }
        // per-layer weight conversion into the shared staging buffers
        tconv_k<<<dim3(96, 32),  256, 0, stream>>>(Wq_f, wq,  1024, 3072);
        tconv_k<<<dim3(32, 32),  256, 0, stream>>>(Wo_f, wo,  1024, 1024);
        tconv_k<<<dim3(128, 32), 256, 0, stream>>>(W1_f, w1t, 1024, 4096);
        tconv_k<<<dim3(32, 128), 256, 0, stream>>>(W2_f, w2t, 4096, 1024);
        if (!base)
            tconv_k<<<dim3(32, 32), 256, 0, stream>>>(zW + (size_t)e * 1024 * 1024, wz, 1024, 1024);

        gemm2_k<0><<<dim3(12, 64), 512, 0, stream>>>(catbf, wq, bq, big, nullptr,
                                                     M_TOK, 3072, 1024, nullptr, nullptr);
        attn_k<<<B_ * 16, 256, 0, stream>>>(big, attno);
        gemm2_k<0><<<dim3(4, 64), 512, 0, stream>>>(attno, wo, bo, tmp, nullptr,
                                                    M_TOK, 1024, 1024, nullptr, nullptr);
        ln_k<0><<<M_TOK, 256, 0, stream>>>(tmp, catbf, l1g, l1b, x1, nullptr);
        gemm2_k<1><<<dim3(16, 64), 512, 0, stream>>>(x1, w1t, bf1, big, nullptr,
                                                     M_TOK, 4096, 1024, nullptr, nullptr);
        gemm2_k<0><<<dim3(4, 64), 512, 0, stream>>>(big, w2t, bf2, tmp, nullptr,
                                                    M_TOK, 1024, 4096, nullptr, nullptr);
        if (base) {
            ln_k<1><<<M_TOK, 256, 0, stream>>>(tmp, x1, l2g, l2b, nullptr, acc);
        } else {
            ln_k<0><<<M_TOK, 256, 0, stream>>>(tmp, x1, l2g, l2b, attno, nullptr);  // x2
            gemm2_k<2><<<dim3(4, 64), 512, 0, stream>>>(attno, wz,
                                                        zb + (size_t)e * 1024, nullptr, nullptr,
                                                        M_TOK, 1024, 1024, coef + e * 256, acc);
        }
    };
    encoder(0, true);
    for (int e = 0; e < 4; ++e) encoder(e + 1, false);

    // final projection: out[b,s,:] = acc_row(b*64+s) @ out_W + out_b
    f2bf_k<<<16384, 256, 0, stream>>>(acc, x1, M_TOK * 1024 / 4);
    gemm2_k<3><<<dim3(2, 64), 512, 0, stream>>>(x1, outWT, outb_, nullptr, (float*)d_out,
                                                M_TOK, 512, 1024, nullptr, nullptr);
}